// Round 1
// baseline (1152.896 us; speedup 1.0000x reference)
//
#include <hip/hip_runtime.h>
#include <hip/hip_bf16.h>
#include <math.h>

// Problem constants (HC2MMoE)
#define B_    16384
#define IN_   1024
#define E_    6
#define D_    20
#define EH1_  256
#define EH2_  128
#define EO_   10
#define GH_   64
#define TH_   64

// ---------------------------------------------------------------------------
// Domain bucketing: histogram -> prefix -> scatter (perm = sample ids sorted
// by domain). Gate weights (256KB/domain) then get L1/L2 reuse within a tile.
// ---------------------------------------------------------------------------
__global__ void k_zero(int* __restrict__ hist) {
    if (threadIdx.x < D_) hist[threadIdx.x] = 0;
}

__global__ void k_hist(const int* __restrict__ dom, int* __restrict__ hist) {
    int g = blockIdx.x * blockDim.x + threadIdx.x;
    if (g < B_) atomicAdd(&hist[dom[g]], 1);
}

__global__ void k_prefix(const int* __restrict__ hist, int* __restrict__ baseA,
                         int* __restrict__ cursor) {
    if (threadIdx.x == 0) {
        int s = 0;
        for (int i = 0; i < D_; ++i) { baseA[i] = s; cursor[i] = s; s += hist[i]; }
    }
}

__global__ void k_scatter(const int* __restrict__ dom, int* __restrict__ cursor,
                          int* __restrict__ perm) {
    int g = blockIdx.x * blockDim.x + threadIdx.x;
    if (g < B_) {
        int pos = atomicAdd(&cursor[dom[g]], 1);
        perm[pos] = g;
    }
}

// ---------------------------------------------------------------------------
// Gate: per (domain,tile) block, 16 samples/block (4 waves x 4 samples each).
// hidden: lane = h (GH=64), wave computes 4 samples' relu(x . Gw1[d] + Gb1).
// logits + softmax via LDS.  Writes gate[b][e] (original sample index).
// ---------------------------------------------------------------------------
__global__ __launch_bounds__(256) void k_gate(
        const float* __restrict__ x, const float* __restrict__ Gw1,
        const float* __restrict__ Gb1, const float* __restrict__ Gw2,
        const float* __restrict__ Gb2, const int* __restrict__ perm,
        const int* __restrict__ baseA, const int* __restrict__ cntA,
        float* __restrict__ gate) {
    const int d = blockIdx.y;
    const int cnt = cntA[d];
    const int start = blockIdx.x * 16;
    if (start >= cnt) return;
    const int base = baseA[d];

    __shared__ float gh[16][GH_ + 1];
    __shared__ float lg[16][E_];
    __shared__ int   bs[16];

    const int t = threadIdx.x;
    const int wave = t >> 6;
    const int lane = t & 63;

    if (t < 16) bs[t] = (start + t < cnt) ? perm[base + start + t] : -1;
    __syncthreads();

    // hidden layer: 4 samples per wave, lane = hidden unit
    const int j0 = wave * 4;
    int s0 = bs[j0 + 0], s1 = bs[j0 + 1], s2 = bs[j0 + 2], s3 = bs[j0 + 3];
    int b0 = s0 < 0 ? 0 : s0, b1 = s1 < 0 ? 0 : s1;
    int b2 = s2 < 0 ? 0 : s2, b3 = s3 < 0 ? 0 : s3;
    const float* w1 = Gw1 + (size_t)d * IN_ * GH_;
    const float* x0 = x + (size_t)b0 * IN_;
    const float* x1 = x + (size_t)b1 * IN_;
    const float* x2 = x + (size_t)b2 * IN_;
    const float* x3 = x + (size_t)b3 * IN_;
    float a0 = 0.f, a1 = 0.f, a2 = 0.f, a3 = 0.f;
    for (int i = 0; i < IN_; ++i) {
        float wv = w1[(size_t)i * GH_ + lane];
        a0 += x0[i] * wv;
        a1 += x1[i] * wv;
        a2 += x2[i] * wv;
        a3 += x3[i] * wv;
    }
    float bias = Gb1[d * GH_ + lane];
    gh[j0 + 0][lane] = fmaxf(a0 + bias, 0.f);
    gh[j0 + 1][lane] = fmaxf(a1 + bias, 0.f);
    gh[j0 + 2][lane] = fmaxf(a2 + bias, 0.f);
    gh[j0 + 3][lane] = fmaxf(a3 + bias, 0.f);
    __syncthreads();

    // logits: 96 threads, (sample j, expert e)
    if (t < 16 * E_) {
        int j = t / E_, e = t - j * E_;
        const float* w2 = Gw2 + (size_t)d * GH_ * E_;
        float s = Gb2[d * E_ + e];
        #pragma unroll 8
        for (int h = 0; h < GH_; ++h) s += gh[j][h] * w2[h * E_ + e];
        lg[j][e] = s;
    }
    __syncthreads();

    // softmax + store
    if (t < 16) {
        int b = bs[t];
        if (b >= 0) {
            float mx = lg[t][0];
            #pragma unroll
            for (int e = 1; e < E_; ++e) mx = fmaxf(mx, lg[t][e]);
            float ex[E_], sum = 0.f;
            #pragma unroll
            for (int e = 0; e < E_; ++e) { ex[e] = expf(lg[t][e] - mx); sum += ex[e]; }
            float inv = 1.f / sum;
            #pragma unroll
            for (int e = 0; e < E_; ++e) gate[(size_t)b * E_ + e] = ex[e] * inv;
        }
    }
}

// ---------------------------------------------------------------------------
// Tiled SGEMM with fused bias + ReLU:  C[m][n] = relu(A[m][:] . W[:][n] + bias)
// 128x128 tile, BK=16, 256 threads, 8x8 microtile. blockIdx.z = expert (local).
// A stride aStride selects shared-A (x, stride 0) vs per-expert A (h1).
// ---------------------------------------------------------------------------
#define BM 128
#define BN 128
#define BK 16
#define TM 8
#define TN 8

__global__ __launch_bounds__(256) void k_gemm(
        const float* __restrict__ A, size_t aStride,
        const float* __restrict__ W, const float* __restrict__ Bias,
        float* __restrict__ C, int M, int N, int K, int eBase) {
    __shared__ float As[BK][BM];
    __shared__ float Bs[BK][BN];

    const int z = blockIdx.z;
    const int eAbs = eBase + z;
    const float* Ae = A + (size_t)z * aStride;
    const float* We = W + (size_t)eAbs * K * N;
    const float* BiasE = Bias + (size_t)eAbs * N;
    float* Ce = C + (size_t)z * (size_t)M * N;

    const int b0 = blockIdx.y * BM;
    const int n0 = blockIdx.x * BN;
    const int t = threadIdx.x;
    const int tx = t & 15;
    const int ty = t >> 4;

    // A-load mapping: thread -> (row = t/4 + p*64, col4 = (t%4)*4)
    const int ar = t >> 2;
    const int ac = (t & 3) * 4;
    // B-load mapping: thread -> (k = t/16, n8 = (t%16)*8)
    const int bk = t >> 4;
    const int bn = (t & 15) * 8;

    float acc[TM][TN] = {};

    for (int k0 = 0; k0 < K; k0 += BK) {
        #pragma unroll
        for (int p = 0; p < 2; ++p) {
            int row = ar + p * 64;
            float4 v = *(const float4*)(Ae + (size_t)(b0 + row) * K + k0 + ac);
            As[ac + 0][row] = v.x;
            As[ac + 1][row] = v.y;
            As[ac + 2][row] = v.z;
            As[ac + 3][row] = v.w;
        }
        #pragma unroll
        for (int p = 0; p < 2; ++p) {
            float4 v = *(const float4*)(We + (size_t)(k0 + bk) * N + n0 + bn + p * 4);
            *(float4*)&Bs[bk][bn + p * 4] = v;
        }
        __syncthreads();

        #pragma unroll
        for (int kk = 0; kk < BK; ++kk) {
            float a[TM], b[TN];
            #pragma unroll
            for (int i = 0; i < TM; ++i) a[i] = As[kk][ty * TM + i];
            #pragma unroll
            for (int j = 0; j < TN; ++j) b[j] = Bs[kk][tx * TN + j];
            #pragma unroll
            for (int i = 0; i < TM; ++i)
                #pragma unroll
                for (int j = 0; j < TN; ++j)
                    acc[i][j] += a[i] * b[j];
        }
        __syncthreads();
    }

    float bi[TN];
    #pragma unroll
    for (int j = 0; j < TN; ++j) bi[j] = BiasE[n0 + tx * TN + j];

    #pragma unroll
    for (int i = 0; i < TM; ++i) {
        int row = b0 + ty * TM + i;
        float v[TN];
        #pragma unroll
        for (int j = 0; j < TN; ++j) v[j] = fmaxf(acc[i][j] + bi[j], 0.f);
        float4 v0 = make_float4(v[0], v[1], v[2], v[3]);
        float4 v1 = make_float4(v[4], v[5], v[6], v[7]);
        *(float4*)(Ce + (size_t)row * N + n0 + tx * TN)     = v0;
        *(float4*)(Ce + (size_t)row * N + n0 + tx * TN + 4) = v1;
    }
}

// ---------------------------------------------------------------------------
// Expert layer 3 (no activation): eo[b][e][o] = h2[e][b][:] . Ew3[e][:][o] + Eb3
// One thread per sample; Ew3 (5KB) staged in LDS.
// ---------------------------------------------------------------------------
__global__ __launch_bounds__(256) void k_eo(
        const float* __restrict__ h2, const float* __restrict__ Ew3,
        const float* __restrict__ Eb3, float* __restrict__ eo, int eBase) {
    __shared__ float w[EH2_ * EO_];
    __shared__ float bias[EO_];
    const int z = blockIdx.y;
    const int eAbs = eBase + z;
    for (int i = threadIdx.x; i < EH2_ * EO_; i += 256)
        w[i] = Ew3[(size_t)eAbs * EH2_ * EO_ + i];
    if (threadIdx.x < EO_) bias[threadIdx.x] = Eb3[eAbs * EO_ + threadIdx.x];
    __syncthreads();

    const int b = blockIdx.x * 256 + threadIdx.x;
    const float* hrow = h2 + (size_t)z * B_ * EH2_ + (size_t)b * EH2_;
    float acc[EO_];
    #pragma unroll
    for (int o = 0; o < EO_; ++o) acc[o] = bias[o];
    for (int k = 0; k < EH2_; k += 4) {
        float4 h4 = *(const float4*)(hrow + k);
        const float hv[4] = {h4.x, h4.y, h4.z, h4.w};
        #pragma unroll
        for (int c = 0; c < 4; ++c)
            #pragma unroll
            for (int o = 0; o < EO_; ++o) acc[o] += hv[c] * w[(k + c) * EO_ + o];
    }
    float* dst = eo + (size_t)b * (E_ * EO_) + eAbs * EO_;
    #pragma unroll
    for (int o = 0; o < EO_; ++o) dst[o] = acc[o];
}

// ---------------------------------------------------------------------------
// Final: per-sample wave. MMoE combine (selected domain), avg expert repr,
// tower (EO->64 relu ->1 sigmoid). lane = tower hidden unit.
// ---------------------------------------------------------------------------
__global__ __launch_bounds__(256) void k_final(
        const float* __restrict__ eo, const float* __restrict__ gate,
        const int* __restrict__ dom,
        const float* __restrict__ Tw1, const float* __restrict__ Tb1,
        const float* __restrict__ Tw2, const float* __restrict__ Tb2,
        float* __restrict__ out) {
    const int wave = threadIdx.x >> 6;
    const int lane = threadIdx.x & 63;
    const int b = blockIdx.x * 4 + wave;
    const int d = dom[b];

    const float* eob = eo + (size_t)b * (E_ * EO_);
    float g[E_];
    #pragma unroll
    for (int e = 0; e < E_; ++e) g[e] = gate[(size_t)b * E_ + e];

    float mmoe[EO_], avg[EO_];
    #pragma unroll
    for (int o = 0; o < EO_; ++o) {
        float m = 0.f, a = 0.f;
        #pragma unroll
        for (int e = 0; e < E_; ++e) {
            float v = eob[e * EO_ + o];
            m += g[e] * v;
            a += v;
        }
        mmoe[o] = m;
        avg[o] = a * (1.0f / E_);
    }

    // tower hidden: lane = h
    float acc = Tb1[d * TH_ + lane];
    #pragma unroll
    for (int o = 0; o < EO_; ++o)
        acc += mmoe[o] * Tw1[(size_t)d * EO_ * TH_ + o * TH_ + lane];
    acc = fmaxf(acc, 0.f);

    float s = acc * Tw2[d * TH_ + lane];
    #pragma unroll
    for (int off = 32; off >= 1; off >>= 1) s += __shfl_xor(s, off, 64);

    if (lane == 0)
        out[b] = 1.f / (1.f + expf(-(s + Tb2[d])));
    if (lane < EO_) {
        out[B_ + (size_t)b * EO_ + lane] = avg[lane];
        out[B_ + (size_t)B_ * EO_ + (size_t)b * EO_ + lane] = mmoe[lane];
    }
}

// ---------------------------------------------------------------------------
extern "C" void kernel_launch(void* const* d_in, const int* in_sizes, int n_in,
                              void* d_out, int out_size, void* d_ws, size_t ws_size,
                              hipStream_t stream) {
    const float* x   = (const float*)d_in[0];
    const int*   dom = (const int*)d_in[1];
    const float* Ew1 = (const float*)d_in[2];
    const float* Eb1 = (const float*)d_in[3];
    const float* Ew2 = (const float*)d_in[4];
    const float* Eb2 = (const float*)d_in[5];
    const float* Ew3 = (const float*)d_in[6];
    const float* Eb3 = (const float*)d_in[7];
    const float* Gw1 = (const float*)d_in[8];
    const float* Gb1 = (const float*)d_in[9];
    const float* Gw2 = (const float*)d_in[10];
    const float* Gb2 = (const float*)d_in[11];
    const float* Tw1 = (const float*)d_in[12];
    const float* Tb1 = (const float*)d_in[13];
    const float* Tw2 = (const float*)d_in[14];
    const float* Tb2 = (const float*)d_in[15];
    float* out = (float*)d_out;

    char* ws = (char*)d_ws;
    size_t off = 0;
    auto take = [&](size_t bytes) -> char* {
        char* p = ws + off;
        off = (off + bytes + 255) & ~(size_t)255;
        return p;
    };
    int*   hist    = (int*)take(D_ * 4);
    int*   baseA   = (int*)take(D_ * 4);
    int*   cursor  = (int*)take(D_ * 4);
    int*   perm    = (int*)take(B_ * 4);
    float* gateBuf = (float*)take((size_t)B_ * E_ * 4);
    float* eoBuf   = (float*)take((size_t)B_ * E_ * EO_ * 4);
    size_t fixed = off;

    // pick largest expert-group size that fits ws
    int G = 1;
    const int cands[4] = {6, 3, 2, 1};
    for (int ci = 0; ci < 4; ++ci) {
        size_t need = fixed + (size_t)cands[ci] * B_ * (EH1_ + EH2_) * 4 + 1024;
        if (need <= ws_size) { G = cands[ci]; break; }
    }
    float* h1 = (float*)take((size_t)G * B_ * EH1_ * 4);
    float* h2 = (float*)take((size_t)G * B_ * EH2_ * 4);

    // domain bucketing
    k_zero<<<dim3(1), dim3(64), 0, stream>>>(hist);
    k_hist<<<dim3(B_ / 256), dim3(256), 0, stream>>>(dom, hist);
    k_prefix<<<dim3(1), dim3(32), 0, stream>>>(hist, baseA, cursor);
    k_scatter<<<dim3(B_ / 256), dim3(256), 0, stream>>>(dom, cursor, perm);

    // gates (selected domain only)
    k_gate<<<dim3((B_ + 15) / 16, D_), dim3(256), 0, stream>>>(
        x, Gw1, Gb1, Gw2, Gb2, perm, baseA, hist, gateBuf);

    // experts
    for (int g0 = 0; g0 < E_; g0 += G) {
        k_gemm<<<dim3(EH1_ / BN, B_ / BM, G), dim3(256), 0, stream>>>(
            x, (size_t)0, Ew1, Eb1, h1, B_, EH1_, IN_, g0);
        k_gemm<<<dim3(EH2_ / BN, B_ / BM, G), dim3(256), 0, stream>>>(
            h1, (size_t)B_ * EH1_, Ew2, Eb2, h2, B_, EH2_, EH1_, g0);
        k_eo<<<dim3(B_ / 256, G), dim3(256), 0, stream>>>(h2, Ew3, Eb3, eoBuf, g0);
    }

    // combine + towers + outputs
    k_final<<<dim3(B_ / 4), dim3(256), 0, stream>>>(
        eoBuf, gateBuf, dom, Tw1, Tb1, Tw2, Tb2, out);
}

// Round 2
// 560.310 us; speedup vs baseline: 2.0576x; 2.0576x over previous
//
#include <hip/hip_runtime.h>
#include <hip/hip_bf16.h>
#include <math.h>

// Problem constants (HC2MMoE)
#define B_    16384
#define IN_   1024
#define E_    6
#define D_    20
#define EH1_  256
#define EH2_  128
#define EO_   10
#define GH_   64
#define TH_   64

typedef short  s16x8 __attribute__((ext_vector_type(8)));   // 8 bf16 = 4 VGPRs
typedef float  f32x4 __attribute__((ext_vector_type(4)));

__device__ inline ushort f2bf(float f) {   // RNE fp32 -> bf16 bits
    union { float f; uint32_t u; } v; v.f = f;
    return (ushort)((v.u + 0x7fffu + ((v.u >> 16) & 1u)) >> 16);
}
__device__ inline float bf2f(ushort u) {
    union { uint32_t u; float f; } v; v.u = ((uint32_t)u) << 16;
    return v.f;
}

#define GLOBAL_LDS16(g, l)                                                     \
    __builtin_amdgcn_global_load_lds(                                          \
        (const __attribute__((address_space(1))) void*)(g),                    \
        (__attribute__((address_space(3))) void*)(l), 16, 0, 0)

// ---------------------------------------------------------------------------
// Domain bucketing
// ---------------------------------------------------------------------------
__global__ void k_zero(int* __restrict__ hist) {
    if (threadIdx.x < D_) hist[threadIdx.x] = 0;
}
__global__ void k_hist(const int* __restrict__ dom, int* __restrict__ hist) {
    int g = blockIdx.x * blockDim.x + threadIdx.x;
    if (g < B_) atomicAdd(&hist[dom[g]], 1);
}
__global__ void k_prefix(const int* __restrict__ hist, int* __restrict__ baseA,
                         int* __restrict__ cursor) {
    if (threadIdx.x == 0) {
        int s = 0;
        for (int i = 0; i < D_; ++i) { baseA[i] = s; cursor[i] = s; s += hist[i]; }
    }
}
__global__ void k_scatter(const int* __restrict__ dom, int* __restrict__ cursor,
                          int* __restrict__ perm) {
    int g = blockIdx.x * blockDim.x + threadIdx.x;
    if (g < B_) {
        int pos = atomicAdd(&cursor[dom[g]], 1);
        perm[pos] = g;
    }
}

// ---------------------------------------------------------------------------
// fp32 -> bf16 convert (x), 4 elems/thread
// ---------------------------------------------------------------------------
__global__ __launch_bounds__(256) void k_cvt(const float* __restrict__ src,
                                             ushort* __restrict__ dst) {
    int i = blockIdx.x * 256 + threadIdx.x;
    float4 v = ((const float4*)src)[i];
    ushort4 o;
    o.x = f2bf(v.x); o.y = f2bf(v.y); o.z = f2bf(v.z); o.w = f2bf(v.w);
    ((ushort4*)dst)[i] = o;
}

// ---------------------------------------------------------------------------
// Weight transpose + convert: W [E][K][N] fp32 -> Wt [E][N][K] bf16
// 32x32 LDS tile, grid (N/32, K/32, E)
// ---------------------------------------------------------------------------
__global__ __launch_bounds__(256) void k_wt(const float* __restrict__ W,
                                            ushort* __restrict__ Wt,
                                            int K, int N) {
    __shared__ float tile[32][33];
    const int e = blockIdx.z;
    const int n0 = blockIdx.x * 32, k0 = blockIdx.y * 32;
    const float* We = W + (size_t)e * K * N;
    ushort* Wte = Wt + (size_t)e * K * N;
    const int lx = threadIdx.x & 31, ly = threadIdx.x >> 5;   // ly 0..7
    #pragma unroll
    for (int r = 0; r < 4; ++r)
        tile[ly + r * 8][lx] = We[(size_t)(k0 + ly + r * 8) * N + n0 + lx];
    __syncthreads();
    #pragma unroll
    for (int r = 0; r < 4; ++r)
        Wte[(size_t)(n0 + ly + r * 8) * K + k0 + lx] = f2bf(tile[lx][ly + r * 8]);
}

// ---------------------------------------------------------------------------
// bf16 MFMA GEMM (m97 structure): C = relu(A . W + bias), bf16 out.
// A [M][K] bf16 (aStride selects shared x vs per-expert h1), Wt [E][N][K] bf16,
// 128x128 tile, BK=32, 256 thr = 4 waves, each wave a 64x64 quadrant as 4x4
// grid of 16x16x32 MFMAs. Staging via global_load_lds width=16.
// ---------------------------------------------------------------------------
#define GBM 128
#define GBN 128
#define GBK 32

__global__ __launch_bounds__(256) void k_mfma_gemm(
        const ushort* __restrict__ A, size_t aStride,
        const ushort* __restrict__ Wt, const float* __restrict__ Bias,
        ushort* __restrict__ C, int M, int N, int K, int eBase) {
    __shared__ ushort As[GBM * GBK];   // [row][k], 32 bf16 (64B) per row
    __shared__ ushort Bs[GBN * GBK];   // [n][k]

    const int z = blockIdx.z;
    const int eAbs = eBase + z;
    const ushort* Ae = A + (size_t)z * aStride;
    const ushort* We = Wt + (size_t)eAbs * (size_t)N * K;
    const float* BiasE = Bias + (size_t)eAbs * N;
    ushort* Ce = C + (size_t)z * (size_t)M * N;

    const int m0 = blockIdx.y * GBM;
    const int n0 = blockIdx.x * GBN;
    const int t = threadIdx.x;
    const int wave = t >> 6;
    const int lane = t & 63;

    // staging: chunk q (0..7) = rows q*16 + lane/4, k-off (lane&3)*8 elems
    const int q0 = wave * 2, q1 = q0 + 1;
    const int sr0 = q0 * 16 + (lane >> 2);
    const int sr1 = q1 * 16 + (lane >> 2);
    const int sk  = (lane & 3) * 8;

    const int quad = lane >> 4;
    const int l16  = lane & 15;
    const int rw = (wave & 1) * 64;   // quadrant row offset
    const int cw = (wave >> 1) * 64;  // quadrant col offset

    f32x4 acc[4][4] = {};

    for (int k0 = 0; k0 < K; k0 += GBK) {
        GLOBAL_LDS16(Ae + (size_t)(m0 + sr0) * K + k0 + sk, As + q0 * 512);
        GLOBAL_LDS16(Ae + (size_t)(m0 + sr1) * K + k0 + sk, As + q1 * 512);
        GLOBAL_LDS16(We + (size_t)(n0 + sr0) * K + k0 + sk, Bs + q0 * 512);
        GLOBAL_LDS16(We + (size_t)(n0 + sr1) * K + k0 + sk, Bs + q1 * 512);
        __syncthreads();

        s16x8 af[4], bf[4];
        #pragma unroll
        for (int i = 0; i < 4; ++i)
            af[i] = *(const s16x8*)&As[(rw + 16 * i + l16) * GBK + quad * 8];
        #pragma unroll
        for (int j = 0; j < 4; ++j)
            bf[j] = *(const s16x8*)&Bs[(cw + 16 * j + l16) * GBK + quad * 8];
        #pragma unroll
        for (int i = 0; i < 4; ++i)
            #pragma unroll
            for (int j = 0; j < 4; ++j)
                acc[i][j] = __builtin_amdgcn_mfma_f32_16x16x32_bf16(
                    af[i], bf[j], acc[i][j], 0, 0, 0);
        __syncthreads();
    }

    // epilogue: C/D layout col = lane&15, row = quad*4 + reg
    float bi[4];
    #pragma unroll
    for (int j = 0; j < 4; ++j) bi[j] = BiasE[n0 + cw + 16 * j + l16];

    #pragma unroll
    for (int i = 0; i < 4; ++i) {
        #pragma unroll
        for (int r = 0; r < 4; ++r) {
            int row = m0 + rw + 16 * i + quad * 4 + r;
            ushort* crow = Ce + (size_t)row * N;
            #pragma unroll
            for (int j = 0; j < 4; ++j) {
                float v = fmaxf(acc[i][j][r] + bi[j], 0.f);
                crow[n0 + cw + 16 * j + l16] = f2bf(v);
            }
        }
    }
}

// ---------------------------------------------------------------------------
// Gate: per (domain,tile) block, 16 samples (4 waves x 4), lane = hidden unit.
// ---------------------------------------------------------------------------
__global__ __launch_bounds__(256) void k_gate(
        const float* __restrict__ x, const float* __restrict__ Gw1,
        const float* __restrict__ Gb1, const float* __restrict__ Gw2,
        const float* __restrict__ Gb2, const int* __restrict__ perm,
        const int* __restrict__ baseA, const int* __restrict__ cntA,
        float* __restrict__ gate) {
    const int d = blockIdx.y;
    const int cnt = cntA[d];
    const int start = blockIdx.x * 16;
    if (start >= cnt) return;
    const int base = baseA[d];

    __shared__ float gh[16][GH_ + 1];
    __shared__ float lg[16][E_];
    __shared__ int   bs[16];

    const int t = threadIdx.x;
    const int wave = t >> 6;
    const int lane = t & 63;

    if (t < 16) bs[t] = (start + t < cnt) ? perm[base + start + t] : -1;
    __syncthreads();

    const int j0 = wave * 4;
    int s0 = bs[j0 + 0], s1 = bs[j0 + 1], s2 = bs[j0 + 2], s3 = bs[j0 + 3];
    int b0 = s0 < 0 ? 0 : s0, b1 = s1 < 0 ? 0 : s1;
    int b2 = s2 < 0 ? 0 : s2, b3 = s3 < 0 ? 0 : s3;
    const float* w1 = Gw1 + (size_t)d * IN_ * GH_;
    const float* x0 = x + (size_t)b0 * IN_;
    const float* x1 = x + (size_t)b1 * IN_;
    const float* x2 = x + (size_t)b2 * IN_;
    const float* x3 = x + (size_t)b3 * IN_;
    float a0 = 0.f, a1 = 0.f, a2 = 0.f, a3 = 0.f;
    for (int i = 0; i < IN_; ++i) {
        float wv = w1[(size_t)i * GH_ + lane];
        a0 += x0[i] * wv;
        a1 += x1[i] * wv;
        a2 += x2[i] * wv;
        a3 += x3[i] * wv;
    }
    float bias = Gb1[d * GH_ + lane];
    gh[j0 + 0][lane] = fmaxf(a0 + bias, 0.f);
    gh[j0 + 1][lane] = fmaxf(a1 + bias, 0.f);
    gh[j0 + 2][lane] = fmaxf(a2 + bias, 0.f);
    gh[j0 + 3][lane] = fmaxf(a3 + bias, 0.f);
    __syncthreads();

    if (t < 16 * E_) {
        int j = t / E_, e = t - j * E_;
        const float* w2 = Gw2 + (size_t)d * GH_ * E_;
        float s = Gb2[d * E_ + e];
        #pragma unroll 8
        for (int h = 0; h < GH_; ++h) s += gh[j][h] * w2[h * E_ + e];
        lg[j][e] = s;
    }
    __syncthreads();

    if (t < 16) {
        int b = bs[t];
        if (b >= 0) {
            float mx = lg[t][0];
            #pragma unroll
            for (int e = 1; e < E_; ++e) mx = fmaxf(mx, lg[t][e]);
            float ex[E_], sum = 0.f;
            #pragma unroll
            for (int e = 0; e < E_; ++e) { ex[e] = expf(lg[t][e] - mx); sum += ex[e]; }
            float inv = 1.f / sum;
            #pragma unroll
            for (int e = 0; e < E_; ++e) gate[(size_t)b * E_ + e] = ex[e] * inv;
        }
    }
}

// ---------------------------------------------------------------------------
// Expert layer 3: eo[b][e][o] = h2[e][b][:] . Ew3[e][:][o] + Eb3   (h2 bf16)
// ---------------------------------------------------------------------------
__global__ __launch_bounds__(256) void k_eo(
        const ushort* __restrict__ h2, const float* __restrict__ Ew3,
        const float* __restrict__ Eb3, float* __restrict__ eo, int eBase) {
    __shared__ float w[EH2_ * EO_];
    const int z = blockIdx.y;
    const int eAbs = eBase + z;
    for (int i = threadIdx.x; i < EH2_ * EO_; i += 256)
        w[i] = Ew3[(size_t)eAbs * EH2_ * EO_ + i];
    __syncthreads();

    const int b = blockIdx.x * 256 + threadIdx.x;
    const ushort* hrow = h2 + (size_t)z * B_ * EH2_ + (size_t)b * EH2_;
    float acc[EO_];
    #pragma unroll
    for (int o = 0; o < EO_; ++o) acc[o] = Eb3[eAbs * EO_ + o];
    for (int k = 0; k < EH2_; k += 4) {
        ushort4 h4 = *(const ushort4*)(hrow + k);
        float hv[4] = {bf2f(h4.x), bf2f(h4.y), bf2f(h4.z), bf2f(h4.w)};
        #pragma unroll
        for (int c = 0; c < 4; ++c)
            #pragma unroll
            for (int o = 0; o < EO_; ++o) acc[o] += hv[c] * w[(k + c) * EO_ + o];
    }
    float* dst = eo + (size_t)b * (E_ * EO_) + eAbs * EO_;
    #pragma unroll
    for (int o = 0; o < EO_; ++o) dst[o] = acc[o];
}

// ---------------------------------------------------------------------------
// Final: MMoE combine + avg + tower, one wave per sample
// ---------------------------------------------------------------------------
__global__ __launch_bounds__(256) void k_final(
        const float* __restrict__ eo, const float* __restrict__ gate,
        const int* __restrict__ dom,
        const float* __restrict__ Tw1, const float* __restrict__ Tb1,
        const float* __restrict__ Tw2, const float* __restrict__ Tb2,
        float* __restrict__ out) {
    const int wave = threadIdx.x >> 6;
    const int lane = threadIdx.x & 63;
    const int b = blockIdx.x * 4 + wave;
    const int d = dom[b];

    const float* eob = eo + (size_t)b * (E_ * EO_);
    float g[E_];
    #pragma unroll
    for (int e = 0; e < E_; ++e) g[e] = gate[(size_t)b * E_ + e];

    float mmoe[EO_], avg[EO_];
    #pragma unroll
    for (int o = 0; o < EO_; ++o) {
        float m = 0.f, a = 0.f;
        #pragma unroll
        for (int e = 0; e < E_; ++e) {
            float v = eob[e * EO_ + o];
            m += g[e] * v;
            a += v;
        }
        mmoe[o] = m;
        avg[o] = a * (1.0f / E_);
    }

    float acc = Tb1[d * TH_ + lane];
    #pragma unroll
    for (int o = 0; o < EO_; ++o)
        acc += mmoe[o] * Tw1[(size_t)d * EO_ * TH_ + o * TH_ + lane];
    acc = fmaxf(acc, 0.f);

    float s = acc * Tw2[d * TH_ + lane];
    #pragma unroll
    for (int off = 32; off >= 1; off >>= 1) s += __shfl_xor(s, off, 64);

    if (lane == 0)
        out[b] = 1.f / (1.f + expf(-(s + Tb2[d])));
    if (lane < EO_) {
        out[B_ + (size_t)b * EO_ + lane] = avg[lane];
        out[B_ + (size_t)B_ * EO_ + (size_t)b * EO_ + lane] = mmoe[lane];
    }
}

// ---------------------------------------------------------------------------
extern "C" void kernel_launch(void* const* d_in, const int* in_sizes, int n_in,
                              void* d_out, int out_size, void* d_ws, size_t ws_size,
                              hipStream_t stream) {
    const float* x   = (const float*)d_in[0];
    const int*   dom = (const int*)d_in[1];
    const float* Ew1 = (const float*)d_in[2];
    const float* Eb1 = (const float*)d_in[3];
    const float* Ew2 = (const float*)d_in[4];
    const float* Eb2 = (const float*)d_in[5];
    const float* Ew3 = (const float*)d_in[6];
    const float* Eb3 = (const float*)d_in[7];
    const float* Gw1 = (const float*)d_in[8];
    const float* Gb1 = (const float*)d_in[9];
    const float* Gw2 = (const float*)d_in[10];
    const float* Gb2 = (const float*)d_in[11];
    const float* Tw1 = (const float*)d_in[12];
    const float* Tb1 = (const float*)d_in[13];
    const float* Tw2 = (const float*)d_in[14];
    const float* Tb2 = (const float*)d_in[15];
    float* out = (float*)d_out;

    char* ws = (char*)d_ws;
    size_t off = 0;
    auto take = [&](size_t bytes) -> char* {
        char* p = ws + off;
        off = (off + bytes + 255) & ~(size_t)255;
        return p;
    };
    int*    hist    = (int*)take(D_ * 4);
    int*    baseA   = (int*)take(D_ * 4);
    int*    cursor  = (int*)take(D_ * 4);
    int*    perm    = (int*)take(B_ * 4);
    float*  gateBuf = (float*)take((size_t)B_ * E_ * 4);
    float*  eoBuf   = (float*)take((size_t)B_ * E_ * EO_ * 4);
    ushort* xb      = (ushort*)take((size_t)B_ * IN_ * 2);
    ushort* W1t     = (ushort*)take((size_t)E_ * IN_ * EH1_ * 2);
    ushort* W2t     = (ushort*)take((size_t)E_ * EH1_ * EH2_ * 2);
    size_t fixed = off;

    int G = 1;
    const int cands[4] = {6, 3, 2, 1};
    for (int ci = 0; ci < 4; ++ci) {
        size_t need = fixed + (size_t)cands[ci] * B_ * (EH1_ + EH2_) * 2 + 1024;
        if (need <= ws_size) { G = cands[ci]; break; }
    }
    ushort* h1 = (ushort*)take((size_t)G * B_ * EH1_ * 2);
    ushort* h2 = (ushort*)take((size_t)G * B_ * EH2_ * 2);

    // conversions
    k_cvt<<<dim3(B_ * IN_ / 4 / 256), dim3(256), 0, stream>>>(x, xb);
    k_wt<<<dim3(EH1_ / 32, IN_ / 32, E_), dim3(256), 0, stream>>>(Ew1, W1t, IN_, EH1_);
    k_wt<<<dim3(EH2_ / 32, EH1_ / 32, E_), dim3(256), 0, stream>>>(Ew2, W2t, EH1_, EH2_);

    // domain bucketing
    k_zero<<<dim3(1), dim3(64), 0, stream>>>(hist);
    k_hist<<<dim3(B_ / 256), dim3(256), 0, stream>>>(dom, hist);
    k_prefix<<<dim3(1), dim3(32), 0, stream>>>(hist, baseA, cursor);
    k_scatter<<<dim3(B_ / 256), dim3(256), 0, stream>>>(dom, cursor, perm);

    // gates (selected domain only)
    k_gate<<<dim3((B_ + 15) / 16, D_), dim3(256), 0, stream>>>(
        x, Gw1, Gb1, Gw2, Gb2, perm, baseA, hist, gateBuf);

    // experts (bf16 MFMA)
    for (int g0 = 0; g0 < E_; g0 += G) {
        k_mfma_gemm<<<dim3(EH1_ / GBN, B_ / GBM, G), dim3(256), 0, stream>>>(
            xb, (size_t)0, W1t, Eb1, h1, B_, EH1_, IN_, g0);
        k_mfma_gemm<<<dim3(EH2_ / GBN, B_ / GBM, G), dim3(256), 0, stream>>>(
            h1, (size_t)B_ * EH1_, W2t, Eb2, h2, B_, EH2_, EH1_, g0);
        k_eo<<<dim3(B_ / 256, G), dim3(256), 0, stream>>>(h2, Ew3, Eb3, eoBuf, g0);
    }

    // combine + towers + outputs
    k_final<<<dim3(B_ / 4), dim3(256), 0, stream>>>(
        eoBuf, gateBuf, dom, Tw1, Tb1, Tw2, Tb2, out);
}

// Round 4
// 371.314 us; speedup vs baseline: 3.1049x; 1.5090x over previous
//
#include <hip/hip_runtime.h>
#include <hip/hip_bf16.h>
#include <math.h>

// Problem constants (HC2MMoE)
#define B_    16384
#define IN_   1024
#define E_    6
#define D_    20
#define EH1_  256
#define EH2_  128
#define EO_   10
#define GH_   64
#define TH_   64

typedef short  s16x8 __attribute__((ext_vector_type(8)));   // 8 bf16 = 4 VGPRs
typedef float  f32x4 __attribute__((ext_vector_type(4)));

__device__ inline ushort f2bf(float f) {   // RNE fp32 -> bf16 bits
    union { float f; uint32_t u; } v; v.f = f;
    return (ushort)((v.u + 0x7fffu + ((v.u >> 16) & 1u)) >> 16);
}
__device__ inline float bf2f(ushort u) {
    union { uint32_t u; float f; } v; v.u = ((uint32_t)u) << 16;
    return v.f;
}

#define GLOBAL_LDS16(g, l)                                                     \
    __builtin_amdgcn_global_load_lds(                                          \
        (const __attribute__((address_space(1))) void*)(g),                    \
        (__attribute__((address_space(3))) void*)(l), 16, 0, 0)

// ---------------------------------------------------------------------------
// Domain bucketing
// ---------------------------------------------------------------------------
__global__ void k_zero(int* __restrict__ hist) {
    if (threadIdx.x < D_) hist[threadIdx.x] = 0;
}
__global__ void k_hist(const int* __restrict__ dom, int* __restrict__ hist) {
    int g = blockIdx.x * blockDim.x + threadIdx.x;
    if (g < B_) atomicAdd(&hist[dom[g]], 1);
}
__global__ void k_prefix(const int* __restrict__ hist, int* __restrict__ baseA,
                         int* __restrict__ cursor) {
    if (threadIdx.x == 0) {
        int s = 0;
        for (int i = 0; i < D_; ++i) { baseA[i] = s; cursor[i] = s; s += hist[i]; }
    }
}
__global__ void k_scatter(const int* __restrict__ dom, int* __restrict__ cursor,
                          int* __restrict__ perm) {
    int g = blockIdx.x * blockDim.x + threadIdx.x;
    if (g < B_) {
        int pos = atomicAdd(&cursor[dom[g]], 1);
        perm[pos] = g;
    }
}

// ---------------------------------------------------------------------------
// fp32 -> bf16 convert (x), 4 elems/thread
// ---------------------------------------------------------------------------
__global__ __launch_bounds__(256) void k_cvt(const float* __restrict__ src,
                                             ushort* __restrict__ dst) {
    int i = blockIdx.x * 256 + threadIdx.x;
    float4 v = ((const float4*)src)[i];
    ushort4 o;
    o.x = f2bf(v.x); o.y = f2bf(v.y); o.z = f2bf(v.z); o.w = f2bf(v.w);
    ((ushort4*)dst)[i] = o;
}

// ---------------------------------------------------------------------------
// Weight transpose + convert: W [Z][K][N] fp32 -> Wt [Z][N][K] bf16
// 32x32 LDS tile, grid (N/32, K/32, Z)
// ---------------------------------------------------------------------------
__global__ __launch_bounds__(256) void k_wt(const float* __restrict__ W,
                                            ushort* __restrict__ Wt,
                                            int K, int N) {
    __shared__ float tile[32][33];
    const int e = blockIdx.z;
    const int n0 = blockIdx.x * 32, k0 = blockIdx.y * 32;
    const float* We = W + (size_t)e * K * N;
    ushort* Wte = Wt + (size_t)e * K * N;
    const int lx = threadIdx.x & 31, ly = threadIdx.x >> 5;   // ly 0..7
    #pragma unroll
    for (int r = 0; r < 4; ++r)
        tile[ly + r * 8][lx] = We[(size_t)(k0 + ly + r * 8) * N + n0 + lx];
    __syncthreads();
    #pragma unroll
    for (int r = 0; r < 4; ++r)
        Wte[(size_t)(n0 + ly + r * 8) * K + k0 + lx] = f2bf(tile[lx][ly + r * 8]);
}

// ---------------------------------------------------------------------------
// bf16 MFMA GEMM (m97 structure): C = relu(A . W + bias), bf16 out.
// 128x128 tile, BK=32, 4 waves each a 64x64 quadrant of 4x4 16x16x32 MFMAs.
// ---------------------------------------------------------------------------
#define GBM 128
#define GBN 128
#define GBK 32

__global__ __launch_bounds__(256) void k_mfma_gemm(
        const ushort* __restrict__ A, size_t aStride,
        const ushort* __restrict__ Wt, const float* __restrict__ Bias,
        ushort* __restrict__ C, int M, int N, int K, int eBase) {
    __shared__ ushort As[GBM * GBK];
    __shared__ ushort Bs[GBN * GBK];

    const int z = blockIdx.z;
    const int eAbs = eBase + z;
    const ushort* Ae = A + (size_t)z * aStride;
    const ushort* We = Wt + (size_t)eAbs * (size_t)N * K;
    const float* BiasE = Bias + (size_t)eAbs * N;
    ushort* Ce = C + (size_t)z * (size_t)M * N;

    const int m0 = blockIdx.y * GBM;
    const int n0 = blockIdx.x * GBN;
    const int t = threadIdx.x;
    const int wave = t >> 6;
    const int lane = t & 63;

    const int q0 = wave * 2, q1 = q0 + 1;
    const int sr0 = q0 * 16 + (lane >> 2);
    const int sr1 = q1 * 16 + (lane >> 2);
    const int sk  = (lane & 3) * 8;

    const int quad = lane >> 4;
    const int l16  = lane & 15;
    const int rw = (wave & 1) * 64;
    const int cw = (wave >> 1) * 64;

    f32x4 acc[4][4] = {};

    for (int k0 = 0; k0 < K; k0 += GBK) {
        GLOBAL_LDS16(Ae + (size_t)(m0 + sr0) * K + k0 + sk, As + q0 * 512);
        GLOBAL_LDS16(Ae + (size_t)(m0 + sr1) * K + k0 + sk, As + q1 * 512);
        GLOBAL_LDS16(We + (size_t)(n0 + sr0) * K + k0 + sk, Bs + q0 * 512);
        GLOBAL_LDS16(We + (size_t)(n0 + sr1) * K + k0 + sk, Bs + q1 * 512);
        __syncthreads();

        s16x8 af[4], bf[4];
        #pragma unroll
        for (int i = 0; i < 4; ++i)
            af[i] = *(const s16x8*)&As[(rw + 16 * i + l16) * GBK + quad * 8];
        #pragma unroll
        for (int j = 0; j < 4; ++j)
            bf[j] = *(const s16x8*)&Bs[(cw + 16 * j + l16) * GBK + quad * 8];
        #pragma unroll
        for (int i = 0; i < 4; ++i)
            #pragma unroll
            for (int j = 0; j < 4; ++j)
                acc[i][j] = __builtin_amdgcn_mfma_f32_16x16x32_bf16(
                    af[i], bf[j], acc[i][j], 0, 0, 0);
        __syncthreads();
    }

    float bi[4];
    #pragma unroll
    for (int j = 0; j < 4; ++j) bi[j] = BiasE[n0 + cw + 16 * j + l16];

    #pragma unroll
    for (int i = 0; i < 4; ++i) {
        #pragma unroll
        for (int r = 0; r < 4; ++r) {
            int row = m0 + rw + 16 * i + quad * 4 + r;
            ushort* crow = Ce + (size_t)row * N;
            #pragma unroll
            for (int j = 0; j < 4; ++j) {
                float v = fmaxf(acc[i][j][r] + bi[j], 0.f);
                crow[n0 + cw + 16 * j + l16] = f2bf(v);
            }
        }
    }
}

// ---------------------------------------------------------------------------
// Gate (MFMA, fully fused): per (domain, 64-row tile) block.
// Gather 64 perm rows of xb; hidden = relu(xb . Gw1t[d]^T + Gb1) via MFMA
// (4 waves, each a 64x16 col slice); then layer-2 logits (64x6, LDS) +
// softmax, scatter to gate[b][e].
// NOTE: layer-2 has 64*E_=384 (row,e) pairs > 256 threads -> MUST loop.
// ---------------------------------------------------------------------------
__global__ __launch_bounds__(256) void k_gate2(
        const ushort* __restrict__ xb, const ushort* __restrict__ Gw1t,
        const float* __restrict__ Gb1, const float* __restrict__ Gw2,
        const float* __restrict__ Gb2, const int* __restrict__ perm,
        const int* __restrict__ baseA, const int* __restrict__ cntA,
        float* __restrict__ gate) {
    const int d = blockIdx.y;
    const int cnt = cntA[d];
    const int start = blockIdx.x * 64;
    if (start >= cnt) return;
    const int base = baseA[d];

    __shared__ ushort As[64 * 32];     // gathered x rows   (4 KB)
    __shared__ ushort Bs[64 * 32];     // Gw1t[d] rows      (4 KB)
    __shared__ int    ridx[64];
    __shared__ float  gh[64][GH_ + 1]; // hidden (fp32)
    __shared__ float  w2s[GH_ * E_];
    __shared__ float  b2s[E_];
    __shared__ float  lg[64][E_];

    const int t = threadIdx.x;
    const int wave = t >> 6;
    const int lane = t & 63;
    const int quad = lane >> 4;
    const int l16  = lane & 15;

    if (t < 64) {
        int p = start + t;
        ridx[t] = (p < cnt) ? perm[base + p] : perm[base];  // clamp OOB
    }
    for (int i = t; i < GH_ * E_; i += 256) w2s[i] = Gw2[(size_t)d * GH_ * E_ + i];
    if (t < E_) b2s[t] = Gb2[d * E_ + t];
    __syncthreads();

    // staging mapping: thread t -> row t>>2 (0..63), k-off (t&3)*8
    const int srow = t >> 2;
    const int myRow = ridx[srow];
    const int sk = (t & 3) * 8;
    const ushort* aRow = xb + (size_t)myRow * IN_ + sk;
    const ushort* bRow = Gw1t + (size_t)d * GH_ * IN_ + (size_t)srow * IN_ + sk;

    f32x4 acc[4] = {};
    for (int k0 = 0; k0 < IN_; k0 += 32) {
        GLOBAL_LDS16(aRow + k0, As + wave * 512);
        GLOBAL_LDS16(bRow + k0, Bs + wave * 512);
        __syncthreads();

        s16x8 bf = *(const s16x8*)&Bs[(wave * 16 + l16) * 32 + quad * 8];
        #pragma unroll
        for (int i = 0; i < 4; ++i) {
            s16x8 af = *(const s16x8*)&As[(16 * i + l16) * 32 + quad * 8];
            acc[i] = __builtin_amdgcn_mfma_f32_16x16x32_bf16(af, bf, acc[i], 0, 0, 0);
        }
        __syncthreads();
    }

    // hidden -> LDS with bias+relu. C layout: col = wave*16+l16, row = 16i+quad*4+r
    const int hcol = wave * 16 + l16;
    float hb = Gb1[d * GH_ + hcol];
    #pragma unroll
    for (int i = 0; i < 4; ++i)
        #pragma unroll
        for (int r = 0; r < 4; ++r)
            gh[16 * i + quad * 4 + r][hcol] = fmaxf(acc[i][r] + hb, 0.f);
    __syncthreads();

    // layer 2: 64 rows x 6 experts = 384 pairs, strided over 256 threads
    for (int p = t; p < 64 * E_; p += 256) {
        int row = p / E_, e = p - row * E_;
        float s = b2s[e];
        #pragma unroll 8
        for (int h = 0; h < GH_; ++h) s += gh[row][h] * w2s[h * E_ + e];
        lg[row][e] = s;
    }
    __syncthreads();

    // softmax + scatter
    if (t < 64 && start + t < cnt) {
        int b = ridx[t];
        float mx = lg[t][0];
        #pragma unroll
        for (int e = 1; e < E_; ++e) mx = fmaxf(mx, lg[t][e]);
        float ex[E_], sum = 0.f;
        #pragma unroll
        for (int e = 0; e < E_; ++e) { ex[e] = expf(lg[t][e] - mx); sum += ex[e]; }
        float inv = 1.f / sum;
        #pragma unroll
        for (int e = 0; e < E_; ++e) gate[(size_t)b * E_ + e] = ex[e] * inv;
    }
}

// ---------------------------------------------------------------------------
// Expert layer 3: eo[b][e][o] = h2[e][b][:] . Ew3[e][:][o] + Eb3   (h2 bf16)
// ---------------------------------------------------------------------------
__global__ __launch_bounds__(256) void k_eo(
        const ushort* __restrict__ h2, const float* __restrict__ Ew3,
        const float* __restrict__ Eb3, float* __restrict__ eo, int eBase) {
    __shared__ float w[EH2_ * EO_];
    const int z = blockIdx.y;
    const int eAbs = eBase + z;
    for (int i = threadIdx.x; i < EH2_ * EO_; i += 256)
        w[i] = Ew3[(size_t)eAbs * EH2_ * EO_ + i];
    __syncthreads();

    const int b = blockIdx.x * 256 + threadIdx.x;
    const ushort* hrow = h2 + (size_t)z * B_ * EH2_ + (size_t)b * EH2_;
    float acc[EO_];
    #pragma unroll
    for (int o = 0; o < EO_; ++o) acc[o] = Eb3[eAbs * EO_ + o];
    for (int k = 0; k < EH2_; k += 4) {
        ushort4 h4 = *(const ushort4*)(hrow + k);
        float hv[4] = {bf2f(h4.x), bf2f(h4.y), bf2f(h4.z), bf2f(h4.w)};
        #pragma unroll
        for (int c = 0; c < 4; ++c)
            #pragma unroll
            for (int o = 0; o < EO_; ++o) acc[o] += hv[c] * w[(k + c) * EO_ + o];
    }
    float* dst = eo + (size_t)b * (E_ * EO_) + eAbs * EO_;
    #pragma unroll
    for (int o = 0; o < EO_; ++o) dst[o] = acc[o];
}

// ---------------------------------------------------------------------------
// Final: MMoE combine + avg + tower, one wave per sample
// ---------------------------------------------------------------------------
__global__ __launch_bounds__(256) void k_final(
        const float* __restrict__ eo, const float* __restrict__ gate,
        const int* __restrict__ dom,
        const float* __restrict__ Tw1, const float* __restrict__ Tb1,
        const float* __restrict__ Tw2, const float* __restrict__ Tb2,
        float* __restrict__ out) {
    const int wave = threadIdx.x >> 6;
    const int lane = threadIdx.x & 63;
    const int b = blockIdx.x * 4 + wave;
    const int d = dom[b];

    const float* eob = eo + (size_t)b * (E_ * EO_);
    float g[E_];
    #pragma unroll
    for (int e = 0; e < E_; ++e) g[e] = gate[(size_t)b * E_ + e];

    float mmoe[EO_], avg[EO_];
    #pragma unroll
    for (int o = 0; o < EO_; ++o) {
        float m = 0.f, a = 0.f;
        #pragma unroll
        for (int e = 0; e < E_; ++e) {
            float v = eob[e * EO_ + o];
            m += g[e] * v;
            a += v;
        }
        mmoe[o] = m;
        avg[o] = a * (1.0f / E_);
    }

    float acc = Tb1[d * TH_ + lane];
    #pragma unroll
    for (int o = 0; o < EO_; ++o)
        acc += mmoe[o] * Tw1[(size_t)d * EO_ * TH_ + o * TH_ + lane];
    acc = fmaxf(acc, 0.f);

    float s = acc * Tw2[d * TH_ + lane];
    #pragma unroll
    for (int off = 32; off >= 1; off >>= 1) s += __shfl_xor(s, off, 64);

    if (lane == 0)
        out[b] = 1.f / (1.f + expf(-(s + Tb2[d])));
    if (lane < EO_) {
        out[B_ + (size_t)b * EO_ + lane] = avg[lane];
        out[B_ + (size_t)B_ * EO_ + (size_t)b * EO_ + lane] = mmoe[lane];
    }
}

// ---------------------------------------------------------------------------
extern "C" void kernel_launch(void* const* d_in, const int* in_sizes, int n_in,
                              void* d_out, int out_size, void* d_ws, size_t ws_size,
                              hipStream_t stream) {
    const float* x   = (const float*)d_in[0];
    const int*   dom = (const int*)d_in[1];
    const float* Ew1 = (const float*)d_in[2];
    const float* Eb1 = (const float*)d_in[3];
    const float* Ew2 = (const float*)d_in[4];
    const float* Eb2 = (const float*)d_in[5];
    const float* Ew3 = (const float*)d_in[6];
    const float* Eb3 = (const float*)d_in[7];
    const float* Gw1 = (const float*)d_in[8];
    const float* Gb1 = (const float*)d_in[9];
    const float* Gw2 = (const float*)d_in[10];
    const float* Gb2 = (const float*)d_in[11];
    const float* Tw1 = (const float*)d_in[12];
    const float* Tb1 = (const float*)d_in[13];
    const float* Tw2 = (const float*)d_in[14];
    const float* Tb2 = (const float*)d_in[15];
    float* out = (float*)d_out;

    char* ws = (char*)d_ws;
    size_t off = 0;
    auto take = [&](size_t bytes) -> char* {
        char* p = ws + off;
        off = (off + bytes + 255) & ~(size_t)255;
        return p;
    };
    int*    hist    = (int*)take(D_ * 4);
    int*    baseA   = (int*)take(D_ * 4);
    int*    cursor  = (int*)take(D_ * 4);
    int*    perm    = (int*)take(B_ * 4);
    float*  gateBuf = (float*)take((size_t)B_ * E_ * 4);
    float*  eoBuf   = (float*)take((size_t)B_ * E_ * EO_ * 4);
    ushort* xb      = (ushort*)take((size_t)B_ * IN_ * 2);
    ushort* W1t     = (ushort*)take((size_t)E_ * IN_ * EH1_ * 2);
    ushort* W2t     = (ushort*)take((size_t)E_ * EH1_ * EH2_ * 2);
    ushort* G1t     = (ushort*)take((size_t)D_ * IN_ * GH_ * 2);
    size_t fixed = off;

    int G = 1;
    const int cands[4] = {6, 3, 2, 1};
    for (int ci = 0; ci < 4; ++ci) {
        size_t need = fixed + (size_t)cands[ci] * B_ * (EH1_ + EH2_) * 2 + 1024;
        if (need <= ws_size) { G = cands[ci]; break; }
    }
    ushort* h1 = (ushort*)take((size_t)G * B_ * EH1_ * 2);
    ushort* h2 = (ushort*)take((size_t)G * B_ * EH2_ * 2);

    // conversions
    k_cvt<<<dim3(B_ * IN_ / 4 / 256), dim3(256), 0, stream>>>(x, xb);
    k_wt<<<dim3(EH1_ / 32, IN_ / 32, E_), dim3(256), 0, stream>>>(Ew1, W1t, IN_, EH1_);
    k_wt<<<dim3(EH2_ / 32, EH1_ / 32, E_), dim3(256), 0, stream>>>(Ew2, W2t, EH1_, EH2_);
    k_wt<<<dim3(GH_ / 32, IN_ / 32, D_), dim3(256), 0, stream>>>(Gw1, G1t, IN_, GH_);

    // domain bucketing
    k_zero<<<dim3(1), dim3(64), 0, stream>>>(hist);
    k_hist<<<dim3(B_ / 256), dim3(256), 0, stream>>>(dom, hist);
    k_prefix<<<dim3(1), dim3(32), 0, stream>>>(hist, baseA, cursor);
    k_scatter<<<dim3(B_ / 256), dim3(256), 0, stream>>>(dom, cursor, perm);

    // gates (selected domain only, MFMA + fused softmax)
    k_gate2<<<dim3((B_ + 63) / 64, D_), dim3(256), 0, stream>>>(
        xb, G1t, Gb1, Gw2, Gb2, perm, baseA, hist, gateBuf);

    // experts (bf16 MFMA)
    for (int g0 = 0; g0 < E_; g0 += G) {
        k_mfma_gemm<<<dim3(EH1_ / GBN, B_ / GBM, G), dim3(256), 0, stream>>>(
            xb, (size_t)0, W1t, Eb1, h1, B_, EH1_, IN_, g0);
        k_mfma_gemm<<<dim3(EH2_ / GBN, B_ / GBM, G), dim3(256), 0, stream>>>(
            h1, (size_t)B_ * EH1_, W2t, Eb2, h2, B_, EH2_, EH1_, g0);
        k_eo<<<dim3(B_ / 256, G), dim3(256), 0, stream>>>(h2, Ew3, Eb3, eoBuf, g0);
    }

    // combine + towers + outputs
    k_final<<<dim3(B_ / 4), dim3(256), 0, stream>>>(
        eoBuf, gateBuf, dom, Tw1, Tb1, Tw2, Tb2, out);
}

// Round 5
// 349.116 us; speedup vs baseline: 3.3023x; 1.0636x over previous
//
#include <hip/hip_runtime.h>
#include <hip/hip_bf16.h>
#include <math.h>

// Problem constants (HC2MMoE)
#define B_    16384
#define IN_   1024
#define E_    6
#define D_    20
#define EH1_  256
#define EH2_  128
#define EO_   10
#define GH_   64
#define TH_   64

typedef short  s16x8 __attribute__((ext_vector_type(8)));   // 8 bf16 = 4 VGPRs
typedef float  f32x4 __attribute__((ext_vector_type(4)));

__device__ inline ushort f2bf(float f) {   // RNE fp32 -> bf16 bits
    union { float f; uint32_t u; } v; v.f = f;
    return (ushort)((v.u + 0x7fffu + ((v.u >> 16) & 1u)) >> 16);
}
__device__ inline float bf2f(ushort u) {
    union { uint32_t u; float f; } v; v.u = ((uint32_t)u) << 16;
    return v.f;
}

#define GLOBAL_LDS16(g, l)                                                     \
    __builtin_amdgcn_global_load_lds(                                          \
        (const __attribute__((address_space(1))) void*)(g),                    \
        (__attribute__((address_space(3))) void*)(l), 16, 0, 0)

// ---------------------------------------------------------------------------
// Domain bucketing (k_zero merged into k_cvt)
// ---------------------------------------------------------------------------
__global__ void k_hist(const int* __restrict__ dom, int* __restrict__ hist) {
    int g = blockIdx.x * blockDim.x + threadIdx.x;
    if (g < B_) atomicAdd(&hist[dom[g]], 1);
}
__global__ void k_prefix(const int* __restrict__ hist, int* __restrict__ baseA,
                         int* __restrict__ cursor) {
    if (threadIdx.x == 0) {
        int s = 0;
        for (int i = 0; i < D_; ++i) { baseA[i] = s; cursor[i] = s; s += hist[i]; }
    }
}
__global__ void k_scatter(const int* __restrict__ dom, int* __restrict__ cursor,
                          int* __restrict__ perm) {
    int g = blockIdx.x * blockDim.x + threadIdx.x;
    if (g < B_) {
        int pos = atomicAdd(&cursor[dom[g]], 1);
        perm[pos] = g;
    }
}

// ---------------------------------------------------------------------------
// fp32 -> bf16 convert (x), 4 elems/thread; block 0 also zeroes hist
// ---------------------------------------------------------------------------
__global__ __launch_bounds__(256) void k_cvt(const float* __restrict__ src,
                                             ushort* __restrict__ dst,
                                             int* __restrict__ hist) {
    if (blockIdx.x == 0 && threadIdx.x < D_) hist[threadIdx.x] = 0;
    int i = blockIdx.x * 256 + threadIdx.x;
    float4 v = ((const float4*)src)[i];
    ushort4 o;
    o.x = f2bf(v.x); o.y = f2bf(v.y); o.z = f2bf(v.z); o.w = f2bf(v.w);
    ((ushort4*)dst)[i] = o;
}

// ---------------------------------------------------------------------------
// Weight transpose + convert: W [Z][K][N] fp32 -> Wt [Z][N][K] bf16
// ---------------------------------------------------------------------------
__global__ __launch_bounds__(256) void k_wt(const float* __restrict__ W,
                                            ushort* __restrict__ Wt,
                                            int K, int N) {
    __shared__ float tile[32][33];
    const int e = blockIdx.z;
    const int n0 = blockIdx.x * 32, k0 = blockIdx.y * 32;
    const float* We = W + (size_t)e * K * N;
    ushort* Wte = Wt + (size_t)e * K * N;
    const int lx = threadIdx.x & 31, ly = threadIdx.x >> 5;   // ly 0..7
    #pragma unroll
    for (int r = 0; r < 4; ++r)
        tile[ly + r * 8][lx] = We[(size_t)(k0 + ly + r * 8) * N + n0 + lx];
    __syncthreads();
    #pragma unroll
    for (int r = 0; r < 4; ++r)
        Wte[(size_t)(n0 + ly + r * 8) * K + k0 + lx] = f2bf(tile[lx][ly + r * 8]);
}

// ---------------------------------------------------------------------------
// XOR bank-swizzle for [row][32-elem K] bf16 tiles staged via global_load_lds:
//   physical granule (row, c) holds global k-chunk  c ^ ((row>>1)&3).
// Store side: lane's global k-offset = ((lane&3) ^ ((row>>1)&3)) * 8.
// Read side:  chunk quad lives at      (quad ^ ((l16>>1)&3)) * 8.
// Makes ds_read_b128 fragment loads hit all 8 bank clusters (was 2).
// ---------------------------------------------------------------------------

// bf16 MFMA GEMM: C = relu(A . W + bias), bf16 out. 128x128 tile, BK=32.
#define GBM 128
#define GBN 128
#define GBK 32

__global__ __launch_bounds__(256) void k_mfma_gemm(
        const ushort* __restrict__ A, size_t aStride,
        const ushort* __restrict__ Wt, const float* __restrict__ Bias,
        ushort* __restrict__ C, int M, int N, int K, int eBase) {
    __shared__ ushort As[GBM * GBK];
    __shared__ ushort Bs[GBN * GBK];

    const int z = blockIdx.z;
    const int eAbs = eBase + z;
    const ushort* Ae = A + (size_t)z * aStride;
    const ushort* We = Wt + (size_t)eAbs * (size_t)N * K;
    const float* BiasE = Bias + (size_t)eAbs * N;
    ushort* Ce = C + (size_t)z * (size_t)M * N;

    const int m0 = blockIdx.y * GBM;
    const int n0 = blockIdx.x * GBN;
    const int t = threadIdx.x;
    const int wave = t >> 6;
    const int lane = t & 63;

    const int q0 = wave * 2, q1 = q0 + 1;
    const int sr0 = q0 * 16 + (lane >> 2);
    const int sr1 = sr0 + 16;                       // (sr1>>1)&3 == (sr0>>1)&3
    const int sw  = ((lane & 3) ^ ((sr0 >> 1) & 3)) * 8;   // swizzled k-off

    const int quad = lane >> 4;
    const int l16  = lane & 15;
    const int qsw  = (quad ^ ((l16 >> 1) & 3)) * 8;        // swizzled read
    const int rw = (wave & 1) * 64;
    const int cw = (wave >> 1) * 64;

    f32x4 acc[4][4] = {};

    for (int k0 = 0; k0 < K; k0 += GBK) {
        GLOBAL_LDS16(Ae + (size_t)(m0 + sr0) * K + k0 + sw, As + q0 * 512);
        GLOBAL_LDS16(Ae + (size_t)(m0 + sr1) * K + k0 + sw, As + q1 * 512);
        GLOBAL_LDS16(We + (size_t)(n0 + sr0) * K + k0 + sw, Bs + q0 * 512);
        GLOBAL_LDS16(We + (size_t)(n0 + sr1) * K + k0 + sw, Bs + q1 * 512);
        __syncthreads();

        s16x8 af[4], bf[4];
        #pragma unroll
        for (int i = 0; i < 4; ++i)
            af[i] = *(const s16x8*)&As[(rw + 16 * i + l16) * GBK + qsw];
        #pragma unroll
        for (int j = 0; j < 4; ++j)
            bf[j] = *(const s16x8*)&Bs[(cw + 16 * j + l16) * GBK + qsw];
        #pragma unroll
        for (int i = 0; i < 4; ++i)
            #pragma unroll
            for (int j = 0; j < 4; ++j)
                acc[i][j] = __builtin_amdgcn_mfma_f32_16x16x32_bf16(
                    af[i], bf[j], acc[i][j], 0, 0, 0);
        __syncthreads();
    }

    float bi[4];
    #pragma unroll
    for (int j = 0; j < 4; ++j) bi[j] = BiasE[n0 + cw + 16 * j + l16];

    #pragma unroll
    for (int i = 0; i < 4; ++i) {
        #pragma unroll
        for (int r = 0; r < 4; ++r) {
            int row = m0 + rw + 16 * i + quad * 4 + r;
            ushort* crow = Ce + (size_t)row * N;
            #pragma unroll
            for (int j = 0; j < 4; ++j) {
                float v = fmaxf(acc[i][j][r] + bi[j], 0.f);
                crow[n0 + cw + 16 * j + l16] = f2bf(v);
            }
        }
    }
}

// ---------------------------------------------------------------------------
// Fused expert L2+L3: h2 = relu(h1 . W2^T + Eb2) [128x128 tile = FULL EH2],
// then eo = h2 . Ew3 + Eb3 in-block (h2 round-trips through LDS: C-layout ->
// A-fragment layout; Ew3 staged as zero-padded 16x128 B operand).
// Grid: (B_/128, G).  LDS union: main loop 16KB, epilogue 38.25KB.
// ---------------------------------------------------------------------------
#define H2P 136   // padded row stride (elems) for h2/E3t epilogue tiles

__global__ __launch_bounds__(256) void k_l2eo(
        const ushort* __restrict__ h1, const ushort* __restrict__ W2t,
        const float* __restrict__ Eb2, const float* __restrict__ Ew3,
        const float* __restrict__ Eb3, float* __restrict__ eo, int eBase) {
    __shared__ __attribute__((aligned(16))) ushort smem[17408 + 16 * H2P];
    ushort* As = smem;            // 128*32 elems (main loop)
    ushort* Bs = smem + 4096;     // 128*32 elems (main loop)

    const int z = blockIdx.y;
    const int eAbs = eBase + z;
    const ushort* Ae = h1 + (size_t)z * B_ * EH1_;
    const ushort* We = W2t + (size_t)eAbs * EH2_ * EH1_;   // [N=128][K=256]

    const int m0 = blockIdx.x * GBM;
    const int t = threadIdx.x;
    const int wave = t >> 6;
    const int lane = t & 63;

    const int q0 = wave * 2, q1 = q0 + 1;
    const int sr0 = q0 * 16 + (lane >> 2);
    const int sr1 = sr0 + 16;
    const int sw  = ((lane & 3) ^ ((sr0 >> 1) & 3)) * 8;

    const int quad = lane >> 4;
    const int l16  = lane & 15;
    const int qsw  = (quad ^ ((l16 >> 1) & 3)) * 8;
    const int rw = (wave & 1) * 64;
    const int cw = (wave >> 1) * 64;

    f32x4 acc[4][4] = {};

    for (int k0 = 0; k0 < EH1_; k0 += GBK) {
        GLOBAL_LDS16(Ae + (size_t)(m0 + sr0) * EH1_ + k0 + sw, As + q0 * 512);
        GLOBAL_LDS16(Ae + (size_t)(m0 + sr1) * EH1_ + k0 + sw, As + q1 * 512);
        GLOBAL_LDS16(We + (size_t)sr0 * EH1_ + k0 + sw, Bs + q0 * 512);
        GLOBAL_LDS16(We + (size_t)sr1 * EH1_ + k0 + sw, Bs + q1 * 512);
        __syncthreads();

        s16x8 af[4], bf[4];
        #pragma unroll
        for (int i = 0; i < 4; ++i)
            af[i] = *(const s16x8*)&As[(rw + 16 * i + l16) * GBK + qsw];
        #pragma unroll
        for (int j = 0; j < 4; ++j)
            bf[j] = *(const s16x8*)&Bs[(cw + 16 * j + l16) * GBK + qsw];
        #pragma unroll
        for (int i = 0; i < 4; ++i)
            #pragma unroll
            for (int j = 0; j < 4; ++j)
                acc[i][j] = __builtin_amdgcn_mfma_f32_16x16x32_bf16(
                    af[i], bf[j], acc[i][j], 0, 0, 0);
        __syncthreads();
    }

    // --- epilogue: h2 tile (bias+relu, bf16) -> LDS in A-readable layout ---
    ushort* h2L = smem;             // [128][H2P]  (reuses As/Bs region)
    ushort* E3t = smem + 128 * H2P; // [16][H2P]   (cols >= EO_ zero)

    float bi[4];
    #pragma unroll
    for (int j = 0; j < 4; ++j) bi[j] = Eb2[eAbs * EH2_ + cw + 16 * j + l16];

    #pragma unroll
    for (int i = 0; i < 4; ++i)
        #pragma unroll
        for (int r = 0; r < 4; ++r) {
            int row = rw + 16 * i + quad * 4 + r;
            #pragma unroll
            for (int j = 0; j < 4; ++j)
                h2L[row * H2P + cw + 16 * j + l16] =
                    f2bf(fmaxf(acc[i][j][r] + bi[j], 0.f));
        }

    // stage Ew3 (fp32 [K=128][EO]) as B operand [col16][k128], zero-padded
    for (int i = t; i < 16 * 128; i += 256) {
        int col = i >> 7, k = i & 127;
        float v = (col < EO_) ? Ew3[(size_t)eAbs * EH2_ * EO_ + k * EO_ + col] : 0.f;
        E3t[col * H2P + k] = f2bf(v);
    }
    __syncthreads();

    // eo MFMA: 8 row-groups of 16; wave handles groups 2w, 2w+1. K=128.
    #pragma unroll
    for (int gi = 0; gi < 2; ++gi) {
        int g = wave * 2 + gi;
        f32x4 acc2 = {};
        #pragma unroll
        for (int kc = 0; kc < 4; ++kc) {
            s16x8 a = *(const s16x8*)&h2L[(g * 16 + l16) * H2P + kc * 32 + quad * 8];
            s16x8 b = *(const s16x8*)&E3t[l16 * H2P + kc * 32 + quad * 8];
            acc2 = __builtin_amdgcn_mfma_f32_16x16x32_bf16(a, b, acc2, 0, 0, 0);
        }
        if (l16 < EO_) {
            float b3 = Eb3[eAbs * EO_ + l16];
            #pragma unroll
            for (int r = 0; r < 4; ++r) {
                int row = m0 + g * 16 + quad * 4 + r;
                eo[(size_t)row * (E_ * EO_) + eAbs * EO_ + l16] = acc2[r] + b3;
            }
        }
    }
}

// ---------------------------------------------------------------------------
// Gate (MFMA, fused): per (domain, 64-row tile) block, with bank swizzle.
// ---------------------------------------------------------------------------
__global__ __launch_bounds__(256) void k_gate2(
        const ushort* __restrict__ xb, const ushort* __restrict__ Gw1t,
        const float* __restrict__ Gb1, const float* __restrict__ Gw2,
        const float* __restrict__ Gb2, const int* __restrict__ perm,
        const int* __restrict__ baseA, const int* __restrict__ cntA,
        float* __restrict__ gate) {
    const int d = blockIdx.y;
    const int cnt = cntA[d];
    const int start = blockIdx.x * 64;
    if (start >= cnt) return;
    const int base = baseA[d];

    __shared__ __attribute__((aligned(16))) ushort As[64 * 32];
    __shared__ __attribute__((aligned(16))) ushort Bs[64 * 32];
    __shared__ int    ridx[64];
    __shared__ float  gh[64][GH_ + 1];
    __shared__ float  w2s[GH_ * E_];
    __shared__ float  b2s[E_];
    __shared__ float  lg[64][E_];

    const int t = threadIdx.x;
    const int wave = t >> 6;
    const int lane = t & 63;
    const int quad = lane >> 4;
    const int l16  = lane & 15;
    const int qsw  = (quad ^ ((l16 >> 1) & 3)) * 8;

    if (t < 64) {
        int p = start + t;
        ridx[t] = (p < cnt) ? perm[base + p] : perm[base];  // clamp OOB
    }
    for (int i = t; i < GH_ * E_; i += 256) w2s[i] = Gw2[(size_t)d * GH_ * E_ + i];
    if (t < E_) b2s[t] = Gb2[d * E_ + t];
    __syncthreads();

    const int srow = t >> 2;
    const int sw   = ((t & 3) ^ ((srow >> 1) & 3)) * 8;
    const int myRow = ridx[srow];
    const ushort* aRow = xb + (size_t)myRow * IN_ + sw;
    const ushort* bRow = Gw1t + (size_t)d * GH_ * IN_ + (size_t)srow * IN_ + sw;

    f32x4 acc[4] = {};
    for (int k0 = 0; k0 < IN_; k0 += 32) {
        GLOBAL_LDS16(aRow + k0, As + wave * 512);
        GLOBAL_LDS16(bRow + k0, Bs + wave * 512);
        __syncthreads();

        s16x8 bf = *(const s16x8*)&Bs[(wave * 16 + l16) * 32 + qsw];
        #pragma unroll
        for (int i = 0; i < 4; ++i) {
            s16x8 af = *(const s16x8*)&As[(16 * i + l16) * 32 + qsw];
            acc[i] = __builtin_amdgcn_mfma_f32_16x16x32_bf16(af, bf, acc[i], 0, 0, 0);
        }
        __syncthreads();
    }

    const int hcol = wave * 16 + l16;
    float hb = Gb1[d * GH_ + hcol];
    #pragma unroll
    for (int i = 0; i < 4; ++i)
        #pragma unroll
        for (int r = 0; r < 4; ++r)
            gh[16 * i + quad * 4 + r][hcol] = fmaxf(acc[i][r] + hb, 0.f);
    __syncthreads();

    // layer 2: 64 rows x 6 experts = 384 pairs, strided over 256 threads
    for (int p = t; p < 64 * E_; p += 256) {
        int row = p / E_, e = p - row * E_;
        float s = b2s[e];
        #pragma unroll 8
        for (int h = 0; h < GH_; ++h) s += gh[row][h] * w2s[h * E_ + e];
        lg[row][e] = s;
    }
    __syncthreads();

    if (t < 64 && start + t < cnt) {
        int b = ridx[t];
        float mx = lg[t][0];
        #pragma unroll
        for (int e = 1; e < E_; ++e) mx = fmaxf(mx, lg[t][e]);
        float ex[E_], sum = 0.f;
        #pragma unroll
        for (int e = 0; e < E_; ++e) { ex[e] = expf(lg[t][e] - mx); sum += ex[e]; }
        float inv = 1.f / sum;
        #pragma unroll
        for (int e = 0; e < E_; ++e) gate[(size_t)b * E_ + e] = ex[e] * inv;
    }
}

// ---------------------------------------------------------------------------
// Final: MMoE combine + avg + tower, one wave per sample
// ---------------------------------------------------------------------------
__global__ __launch_bounds__(256) void k_final(
        const float* __restrict__ eo, const float* __restrict__ gate,
        const int* __restrict__ dom,
        const float* __restrict__ Tw1, const float* __restrict__ Tb1,
        const float* __restrict__ Tw2, const float* __restrict__ Tb2,
        float* __restrict__ out) {
    const int wave = threadIdx.x >> 6;
    const int lane = threadIdx.x & 63;
    const int b = blockIdx.x * 4 + wave;
    const int d = dom[b];

    const float* eob = eo + (size_t)b * (E_ * EO_);
    float g[E_];
    #pragma unroll
    for (int e = 0; e < E_; ++e) g[e] = gate[(size_t)b * E_ + e];

    float mmoe[EO_], avg[EO_];
    #pragma unroll
    for (int o = 0; o < EO_; ++o) {
        float m = 0.f, a = 0.f;
        #pragma unroll
        for (int e = 0; e < E_; ++e) {
            float v = eob[e * EO_ + o];
            m += g[e] * v;
            a += v;
        }
        mmoe[o] = m;
        avg[o] = a * (1.0f / E_);
    }

    float acc = Tb1[d * TH_ + lane];
    #pragma unroll
    for (int o = 0; o < EO_; ++o)
        acc += mmoe[o] * Tw1[(size_t)d * EO_ * TH_ + o * TH_ + lane];
    acc = fmaxf(acc, 0.f);

    float s = acc * Tw2[d * TH_ + lane];
    #pragma unroll
    for (int off = 32; off >= 1; off >>= 1) s += __shfl_xor(s, off, 64);

    if (lane == 0)
        out[b] = 1.f / (1.f + expf(-(s + Tb2[d])));
    if (lane < EO_) {
        out[B_ + (size_t)b * EO_ + lane] = avg[lane];
        out[B_ + (size_t)B_ * EO_ + (size_t)b * EO_ + lane] = mmoe[lane];
    }
}

// ---------------------------------------------------------------------------
extern "C" void kernel_launch(void* const* d_in, const int* in_sizes, int n_in,
                              void* d_out, int out_size, void* d_ws, size_t ws_size,
                              hipStream_t stream) {
    const float* x   = (const float*)d_in[0];
    const int*   dom = (const int*)d_in[1];
    const float* Ew1 = (const float*)d_in[2];
    const float* Eb1 = (const float*)d_in[3];
    const float* Ew2 = (const float*)d_in[4];
    const float* Eb2 = (const float*)d_in[5];
    const float* Ew3 = (const float*)d_in[6];
    const float* Eb3 = (const float*)d_in[7];
    const float* Gw1 = (const float*)d_in[8];
    const float* Gb1 = (const float*)d_in[9];
    const float* Gw2 = (const float*)d_in[10];
    const float* Gb2 = (const float*)d_in[11];
    const float* Tw1 = (const float*)d_in[12];
    const float* Tb1 = (const float*)d_in[13];
    const float* Tw2 = (const float*)d_in[14];
    const float* Tb2 = (const float*)d_in[15];
    float* out = (float*)d_out;

    char* ws = (char*)d_ws;
    size_t off = 0;
    auto take = [&](size_t bytes) -> char* {
        char* p = ws + off;
        off = (off + bytes + 255) & ~(size_t)255;
        return p;
    };
    int*    hist    = (int*)take(D_ * 4);
    int*    baseA   = (int*)take(D_ * 4);
    int*    cursor  = (int*)take(D_ * 4);
    int*    perm    = (int*)take(B_ * 4);
    float*  gateBuf = (float*)take((size_t)B_ * E_ * 4);
    float*  eoBuf   = (float*)take((size_t)B_ * E_ * EO_ * 4);
    ushort* xb      = (ushort*)take((size_t)B_ * IN_ * 2);
    ushort* W1t     = (ushort*)take((size_t)E_ * IN_ * EH1_ * 2);
    ushort* W2t     = (ushort*)take((size_t)E_ * EH1_ * EH2_ * 2);
    ushort* G1t     = (ushort*)take((size_t)D_ * IN_ * GH_ * 2);
    size_t fixed = off;

    int G = 1;
    const int cands[4] = {6, 3, 2, 1};
    for (int ci = 0; ci < 4; ++ci) {
        size_t need = fixed + (size_t)cands[ci] * B_ * EH1_ * 2 + 1024;
        if (need <= ws_size) { G = cands[ci]; break; }
    }
    ushort* h1 = (ushort*)take((size_t)G * B_ * EH1_ * 2);

    // conversions (+hist zero inside k_cvt)
    k_cvt<<<dim3(B_ * IN_ / 4 / 256), dim3(256), 0, stream>>>(x, xb, hist);
    k_wt<<<dim3(EH1_ / 32, IN_ / 32, E_), dim3(256), 0, stream>>>(Ew1, W1t, IN_, EH1_);
    k_wt<<<dim3(EH2_ / 32, EH1_ / 32, E_), dim3(256), 0, stream>>>(Ew2, W2t, EH1_, EH2_);
    k_wt<<<dim3(GH_ / 32, IN_ / 32, D_), dim3(256), 0, stream>>>(Gw1, G1t, IN_, GH_);

    // domain bucketing
    k_hist<<<dim3(B_ / 256), dim3(256), 0, stream>>>(dom, hist);
    k_prefix<<<dim3(1), dim3(32), 0, stream>>>(hist, baseA, cursor);
    k_scatter<<<dim3(B_ / 256), dim3(256), 0, stream>>>(dom, cursor, perm);

    // gates (selected domain only, MFMA + fused softmax)
    k_gate2<<<dim3((B_ + 63) / 64, D_), dim3(256), 0, stream>>>(
        xb, G1t, Gb1, Gw2, Gb2, perm, baseA, hist, gateBuf);

    // experts: L1 MFMA gemm, then fused L2+L3
    for (int g0 = 0; g0 < E_; g0 += G) {
        k_mfma_gemm<<<dim3(EH1_ / GBN, B_ / GBM, G), dim3(256), 0, stream>>>(
            xb, (size_t)0, W1t, Eb1, h1, B_, EH1_, IN_, g0);
        k_l2eo<<<dim3(B_ / GBM, G), dim3(256), 0, stream>>>(
            h1, W2t, Eb2, Ew3, Eb3, eoBuf, g0);
    }

    // combine + towers + outputs
    k_final<<<dim3(B_ / 4), dim3(256), 0, stream>>>(
        eoBuf, gateBuf, dom, Tw1, Tb1, Tw2, Tb2, out);
}